// Round 6
// baseline (774.663 us; speedup 1.0000x reference)
//
#include <hip/hip_runtime.h>
#include <hip/hip_bf16.h>

// GraphSAGE 3-layer, N=50000 nodes, E=400000 edges, dims 512->512->512->128.
// Round 13 -> 14:
//  R1-R5 postmortem: all K-loop variants flat at ~110us with ALL pipes idle
//  (Mfma 19%, VALU 13%, HBM 16%) and hard floors at <=31us -> latency-bound
//  with only ~2.3 barrier-coupled block pipelines resident per CU (unified
//  VGPR+AGPR ~136/wave caps 3 waves/SIMD; every prior edit stayed INSIDE one
//  pipeline). Fix: 64x64 tiles, ONE WAVE per block, ZERO barriers -- 16KB LDS
//  -> ~10 independent per-CU pipelines, each self-ordered by counted vmcnt
//  (stage it+1's 8 loads; vmcnt(8) waits only for it's; ds_read+MFMA).
//  Same swizzle involution (row-group offsets are 0 mod 4 so (row>>1)&3
//  is unchanged); sched_barrier(0) after waitcnt per rule #18.

#define N_NODES 50000
#define N_EDGES 400000

typedef unsigned short u16;
typedef unsigned int u32;
typedef __attribute__((ext_vector_type(8))) short short8;
typedef __attribute__((ext_vector_type(4))) float floatx4;

#define ASYNC16(g, l)                                                      \
    __builtin_amdgcn_global_load_lds(                                      \
        (const __attribute__((address_space(1))) void*)(g),                \
        (__attribute__((address_space(3))) void*)(l), 16, 0, 0)

__device__ __forceinline__ u16 f32_to_bf16(float f) {
    u32 u = __float_as_uint(f);
    u32 r = 0x7FFFu + ((u >> 16) & 1u);
    return (u16)((u + r) >> 16);
}
__device__ __forceinline__ float bf16_to_f32(u32 lo16) {
    return __uint_as_float(lo16 << 16);
}

__global__ __launch_bounds__(256) void zero4_kernel(float4* __restrict__ p, int n4) {
    int i = blockIdx.x * 256 + threadIdx.x;
    if (i < n4) p[i] = make_float4(0.f, 0.f, 0.f, 0.f);
}

__global__ __launch_bounds__(256) void hist_kernel(const int* __restrict__ dst,
                                                   int* __restrict__ deg, int E) {
    int e = blockIdx.x * 256 + threadIdx.x;
    if (e < E) atomicAdd(&deg[dst[e]], 1);
}

__global__ __launch_bounds__(256) void scan_reduce(const int* __restrict__ v,
                                                   int* __restrict__ bsums, int n) {
    __shared__ int sh[256];
    int i = blockIdx.x * 256 + threadIdx.x;
    sh[threadIdx.x] = (i < n) ? v[i] : 0;
    __syncthreads();
    for (int off = 128; off > 0; off >>= 1) {
        if (threadIdx.x < off) sh[threadIdx.x] += sh[threadIdx.x + off];
        __syncthreads();
    }
    if (threadIdx.x == 0) bsums[blockIdx.x] = sh[0];
}

__global__ __launch_bounds__(256) void scan_sums(int* __restrict__ bsums, int nb) {
    __shared__ int sh[256];
    int t = threadIdx.x;
    int val = (t < nb) ? bsums[t] : 0;
    sh[t] = val;
    __syncthreads();
    for (int off = 1; off < 256; off <<= 1) {
        int v = (t >= off) ? sh[t - off] : 0;
        __syncthreads();
        sh[t] += v;
        __syncthreads();
    }
    if (t < nb) bsums[t] = sh[t] - val;
}

__global__ __launch_bounds__(256) void scan_final(int* __restrict__ v,
                                                  const int* __restrict__ bsums, int n) {
    __shared__ int sh[256];
    int t = threadIdx.x;
    int i = blockIdx.x * 256 + t;
    int val = (i < n) ? v[i] : 0;
    sh[t] = val;
    __syncthreads();
    for (int off = 1; off < 256; off <<= 1) {
        int x = (t >= off) ? sh[t - off] : 0;
        __syncthreads();
        sh[t] += x;
        __syncthreads();
    }
    int excl = sh[t] - val + bsums[blockIdx.x];
    if (i < n) v[i] = excl;
    if (i == n - 1) v[n] = excl + val;
}

__global__ __launch_bounds__(256) void fill_kernel(const int* __restrict__ src,
                                                   const int* __restrict__ dst,
                                                   const int* __restrict__ row_start,
                                                   int* __restrict__ cursor,
                                                   int* __restrict__ csr_src, int E) {
    int e = blockIdx.x * 256 + threadIdx.x;
    if (e < E) {
        int d = dst[e];
        int pos = row_start[d] + atomicAdd(&cursor[d], 1);
        csr_src[pos] = src[e];
    }
}

// f32 [n8*8] -> bf16, 8 elems/thread
__global__ __launch_bounds__(256) void convert_bf16(const float* __restrict__ in,
                                                    u16* __restrict__ out, int n8) {
    int i = blockIdx.x * 256 + threadIdx.x;
    if (i >= n8) return;
    const float4* p = (const float4*)in + (size_t)i * 2;
    float4 v0 = p[0], v1 = p[1];
    uint4 o;
    o.x = (u32)f32_to_bf16(v0.x) | ((u32)f32_to_bf16(v0.y) << 16);
    o.y = (u32)f32_to_bf16(v0.z) | ((u32)f32_to_bf16(v0.w) << 16);
    o.z = (u32)f32_to_bf16(v1.x) | ((u32)f32_to_bf16(v1.y) << 16);
    o.w = (u32)f32_to_bf16(v1.z) | ((u32)f32_to_bf16(v1.w) << 16);
    ((uint4*)out)[i] = o;
}

// W [K][N] f32 -> WT [N][K] bf16, 32x32 tiles
__global__ __launch_bounds__(256) void transpose_w(const float* __restrict__ W,
                                                   u16* __restrict__ WT,
                                                   int K, int N) {
    __shared__ float t[32][33];
    int n0 = blockIdx.x * 32, k0 = blockIdx.y * 32;
    int c = threadIdx.x & 31, r0 = threadIdx.x >> 5;
    for (int r = r0; r < 32; r += 8)
        t[r][c] = W[(size_t)(k0 + r) * N + n0 + c];
    __syncthreads();
    for (int r = r0; r < 32; r += 8)
        WT[(size_t)(n0 + r) * K + k0 + c] = f32_to_bf16(t[c][r]);
}

// C = A @ BT' (BT stored [N][512], k-contig), single pass K=512, bf16 out.
// 64x64 tile, ONE 64-lane wave per block, NO barriers: private dbuf LDS
// (8KB A + 8KB B), counted-vmcnt self-pipeline -- stage(it+1) 8 loads, then
// s_waitcnt vmcnt(8) (drains it's loads only), ds_read frags, 16 MFMA.
// global_load_lds lane-linear dest + source-swizzled (rule 21 involution:
// stored chunk sc holds global chunk sc^((row>>1)&3); reader uses kq^swz).
// Swapped-operand MFMA (C^T regs). Output split: col0<split -> Cl else Cr.
__global__ __launch_bounds__(64) void gemm_bf16(
    const u16* __restrict__ A, const u16* __restrict__ BT,
    u16* __restrict__ Cl, u16* __restrict__ Cr,
    int M, int split, int nStrips, int nCols) {
    __shared__ u16 As[2][2048];  // 64 rows x 32 u16 (64B)
    __shared__ u16 Bs[2][2048];

    const int grp = 8 * nCols;
    int b = blockIdx.x;
    int strip = (b / grp) * 8 + (b & 7);   // col-tiles of a strip share b%8 -> XCD
    int colt = (b % grp) >> 3;
    if (strip >= nStrips) return;
    const int row0 = strip * 64, col0 = colt * 64;

    const int lane = threadIdx.x;          // 0..63
    const int l15 = lane & 15, kq = lane >> 4;
    const int swz = (l15 >> 1) & 3;        // fragment-read swizzle bits

    floatx4 acc[4][4];
#pragma unroll
    for (int i = 0; i < 4; ++i)
#pragma unroll
        for (int j = 0; j < 4; ++j) acc[i][j] = floatx4{0.f, 0.f, 0.f, 0.f};

    // Staging: per iter, A-tile = 64 rows x 64B = 4KB = 4 wave-instructions
    // (rows 16g+sr, g=0..3); same for B. Lane -> sr = lane>>2, sc = lane&3.
    // swzS = ((16g+sr)>>1)&3 = (sr>>1)&3 (16g/2 = 8g ≡ 0 mod 4).
    const int sr = lane >> 2;
    const int sc = lane & 3;
    const int swzS = (sr >> 1) & 3;
    // Global row offsets for the 4 row-groups, clamped (A only).
    size_t aoff[4], boff[4];
#pragma unroll
    for (int g = 0; g < 4; ++g) {
        aoff[g] = (size_t)min(row0 + g * 16 + sr, M - 1) * 512 + (sc ^ swzS) * 8;
        boff[g] = (size_t)(col0 + g * 16 + sr) * 512 + (sc ^ swzS) * 8;
    }

    auto stage = [&](int it, int buf) {
        const int eff = it * 32;
#pragma unroll
        for (int g = 0; g < 4; ++g) {
            ASYNC16(A + aoff[g] + eff, &As[buf][g * 512]);  // 512 u16 = 1KB window
            ASYNC16(BT + boff[g] + eff, &Bs[buf][g * 512]);
        }
    };

    stage(0, 0);
    for (int it = 0; it < 16; ++it) {
        const int buf = it & 1;
        if (it + 1 < 16) {
            stage(it + 1, buf ^ 1);
            asm volatile("s_waitcnt vmcnt(8)" ::: "memory");  // it's 8 done
        } else {
            asm volatile("s_waitcnt vmcnt(0)" ::: "memory");
        }
        __builtin_amdgcn_sched_barrier(0);  // pin ds_reads below the wait

        const int kc = (kq ^ swz) * 8;      // swizzled chunk for this lane
        short8 a[4], bfr[4];
#pragma unroll
        for (int mt = 0; mt < 4; ++mt)
            a[mt] = *(const short8*)&As[buf][(mt * 16 + l15) * 32 + kc];
#pragma unroll
        for (int nt = 0; nt < 4; ++nt)
            bfr[nt] = *(const short8*)&Bs[buf][(nt * 16 + l15) * 32 + kc];
        // Swapped operands: D = C^T; lane l15 = C-row, regs = 4 consecutive cols
#pragma unroll
        for (int mt = 0; mt < 4; ++mt)
#pragma unroll
            for (int nt = 0; nt < 4; ++nt)
                acc[mt][nt] = __builtin_amdgcn_mfma_f32_16x16x32_bf16(
                    bfr[nt], a[mt], acc[mt][nt], 0, 0, 0);
    }

    // Epilogue (C^T layout): row = row0+mt*16+l15, cols = col0+nt*16+kq*4..+3
    u16* __restrict__ Cbase = (col0 < split) ? Cl : Cr;
    const int cadj = (col0 < split) ? col0 : (col0 - split);
#pragma unroll
    for (int mt = 0; mt < 4; ++mt) {
        int row = row0 + mt * 16 + l15;
        if (row >= M) continue;
#pragma unroll
        for (int nt = 0; nt < 4; ++nt) {
            int c0 = cadj + nt * 16 + kq * 4;
            uint2 o;
            o.x = (u32)f32_to_bf16(acc[mt][nt][0]) |
                  ((u32)f32_to_bf16(acc[mt][nt][1]) << 16);
            o.y = (u32)f32_to_bf16(acc[mt][nt][2]) |
                  ((u32)f32_to_bf16(acc[mt][nt][3]) << 16);
            *(uint2*)(Cbase + (size_t)row * split + c0) = o;
        }
    }
}

// h[node] = relu(mean(Yl[src]) + Yr[node] + bias), D=512 bf16.
// One wave per node; lane covers 8 cols (uint4).
__global__ __launch_bounds__(256) void gather_add_relu512(
    const u16* __restrict__ Yl, const u16* __restrict__ Yr,
    const float* __restrict__ bias,
    const int* __restrict__ row_start, const int* __restrict__ csr_src,
    u16* __restrict__ h, int M) {
    int node = (blockIdx.x * 256 + threadIdx.x) >> 6;
    int lane = threadIdx.x & 63;
    if (node >= M) return;
    int beg = row_start[node], end = row_start[node + 1];
    float a[8] = {0.f, 0.f, 0.f, 0.f, 0.f, 0.f, 0.f, 0.f};
    for (int c = beg; c < end; c += 64) {
        int nb = min(64, end - c);
        int eid = (lane < nb) ? csr_src[c + lane] : 0;
        for (int i = 0; i < nb; ++i) {
            int s = __shfl(eid, i);
            uint4 v = ((const uint4*)(Yl + (size_t)s * 512))[lane];
            a[0] += bf16_to_f32(v.x & 0xffffu); a[1] += bf16_to_f32(v.x >> 16);
            a[2] += bf16_to_f32(v.y & 0xffffu); a[3] += bf16_to_f32(v.y >> 16);
            a[4] += bf16_to_f32(v.z & 0xffffu); a[5] += bf16_to_f32(v.z >> 16);
            a[6] += bf16_to_f32(v.w & 0xffffu); a[7] += bf16_to_f32(v.w >> 16);
        }
    }
    float inv = 1.0f / fmaxf((float)(end - beg), 1.0f);
    uint4 yr = ((const uint4*)(Yr + (size_t)node * 512))[lane];
    float4 b0 = ((const float4*)bias)[lane * 2];
    float4 b1 = ((const float4*)bias)[lane * 2 + 1];
    float v0 = fmaxf(a[0] * inv + bf16_to_f32(yr.x & 0xffffu) + b0.x, 0.f);
    float v1 = fmaxf(a[1] * inv + bf16_to_f32(yr.x >> 16)     + b0.y, 0.f);
    float v2 = fmaxf(a[2] * inv + bf16_to_f32(yr.y & 0xffffu) + b0.z, 0.f);
    float v3 = fmaxf(a[3] * inv + bf16_to_f32(yr.y >> 16)     + b0.w, 0.f);
    float v4 = fmaxf(a[4] * inv + bf16_to_f32(yr.z & 0xffffu) + b1.x, 0.f);
    float v5 = fmaxf(a[5] * inv + bf16_to_f32(yr.z >> 16)     + b1.y, 0.f);
    float v6 = fmaxf(a[6] * inv + bf16_to_f32(yr.w & 0xffffu) + b1.z, 0.f);
    float v7 = fmaxf(a[7] * inv + bf16_to_f32(yr.w >> 16)     + b1.w, 0.f);
    uint4 o;
    o.x = (u32)f32_to_bf16(v0) | ((u32)f32_to_bf16(v1) << 16);
    o.y = (u32)f32_to_bf16(v2) | ((u32)f32_to_bf16(v3) << 16);
    o.z = (u32)f32_to_bf16(v4) | ((u32)f32_to_bf16(v5) << 16);
    o.w = (u32)f32_to_bf16(v6) | ((u32)f32_to_bf16(v7) << 16);
    ((uint4*)(h + (size_t)node * 512))[lane] = o;
}

// out[node] = log_softmax(mean(Yl[src]) + Yr[node] + bias), D=128, f32 out.
// 16 lanes per node (4 nodes/wave); lane covers 8 cols.
__global__ __launch_bounds__(256) void gather_add_lsm128(
    const u16* __restrict__ Yl, const u16* __restrict__ Yr,
    const float* __restrict__ bias,
    const int* __restrict__ row_start, const int* __restrict__ csr_src,
    float* __restrict__ out, int M) {
    int node = blockIdx.x * 16 + (threadIdx.x >> 4);
    int lane = threadIdx.x & 63;
    int li = lane & 15;
    int gbase = lane & 48;      // group base lane within wave
    if (node >= M) return;
    int beg = row_start[node], end = row_start[node + 1];
    float a[8] = {0.f, 0.f, 0.f, 0.f, 0.f, 0.f, 0.f, 0.f};
    for (int c = beg; c < end; c += 16) {
        int nb = min(16, end - c);
        int eid = (li < nb) ? csr_src[c + li] : 0;
        for (int i = 0; i < nb; ++i) {
            int s = __shfl(eid, gbase + i);
            uint4 v = ((const uint4*)(Yl + (size_t)s * 128))[li];
            a[0] += bf16_to_f32(v.x & 0xffffu); a[1] += bf16_to_f32(v.x >> 16);
            a[2] += bf16_to_f32(v.y & 0xffffu); a[3] += bf16_to_f32(v.y >> 16);
            a[4] += bf16_to_f32(v.z & 0xffffu); a[5] += bf16_to_f32(v.z >> 16);
            a[6] += bf16_to_f32(v.w & 0xffffu); a[7] += bf16_to_f32(v.w >> 16);
        }
    }
    float inv = 1.0f / fmaxf((float)(end - beg), 1.0f);
    uint4 yr = ((const uint4*)(Yr + (size_t)node * 128))[li];
    float4 b0 = ((const float4*)bias)[li * 2];
    float4 b1 = ((const float4*)bias)[li * 2 + 1];
    float v[8];
    v[0] = a[0] * inv + bf16_to_f32(yr.x & 0xffffu) + b0.x;
    v[1] = a[1] * inv + bf16_to_f32(yr.x >> 16)     + b0.y;
    v[2] = a[2] * inv + bf16_to_f32(yr.y & 0xffffu) + b0.z;
    v[3] = a[3] * inv + bf16_to_f32(yr.y >> 16)     + b0.w;
    v[4] = a[4] * inv + bf16_to_f32(yr.z & 0xffffu) + b1.x;
    v[5] = a[5] * inv + bf16_to_f32(yr.z >> 16)     + b1.y;
    v[6] = a[6] * inv + bf16_to_f32(yr.w & 0xffffu) + b1.z;
    v[7] = a[7] * inv + bf16_to_f32(yr.w >> 16)     + b1.w;
    float m = v[0];
#pragma unroll
    for (int j = 1; j < 8; ++j) m = fmaxf(m, v[j]);
#pragma unroll
    for (int off = 1; off < 16; off <<= 1) m = fmaxf(m, __shfl_xor(m, off));
    float s = 0.f;
#pragma unroll
    for (int j = 0; j < 8; ++j) s += expf(v[j] - m);
#pragma unroll
    for (int off = 1; off < 16; off <<= 1) s += __shfl_xor(s, off);
    float ls = m + logf(s);
    float* p = out + (size_t)node * 128 + li * 8;
    *(float4*)p       = make_float4(v[0] - ls, v[1] - ls, v[2] - ls, v[3] - ls);
    *(float4*)(p + 4) = make_float4(v[4] - ls, v[5] - ls, v[6] - ls, v[7] - ls);
}

extern "C" void kernel_launch(void* const* d_in, const int* in_sizes, int n_in,
                              void* d_out, int out_size, void* d_ws, size_t ws_size,
                              hipStream_t stream) {
    const float* x    = (const float*)d_in[0];
    const int*   ei   = (const int*)d_in[1];
    const float* W1_l = (const float*)d_in[2];
    const float* b1   = (const float*)d_in[3];
    const float* W1_r = (const float*)d_in[4];
    const float* W2_l = (const float*)d_in[5];
    const float* b2   = (const float*)d_in[6];
    const float* W2_r = (const float*)d_in[7];
    const float* W3_l = (const float*)d_in[8];
    const float* b3   = (const float*)d_in[9];
    const float* W3_r = (const float*)d_in[10];
    float* out = (float*)d_out;

    const int* src = ei;
    const int* dst = ei + N_EDGES;

    // Workspace layout (bytes from base):
    char* base = (char*)d_ws;
    int* row_start = (int*)(base);                    // 50052 ints
    int* cursor    = (int*)(base + 200208);           // 50052 ints
    int* bsums     = (int*)(base + 400416);           // 512 ints
    int* csr_src   = (int*)(base + 402464);           // 400000 ints -> end 2002464
    u16* xb  = (u16*)(base + 2002464);                // [M][512] bf16
    u16* h1b = (u16*)(base + 53202464);               // [M][512]
    u16* h2b = (u16*)(base + 104402464);              // [M][512]
    u16* Yl  = (u16*)(base + 155602464);              // [M][512] (layer3: [M][128])
    u16* Yr  = (u16*)(base + 206802464);              // [M][512] (layer3: [M][128])
    u16* w1T = (u16*)(base + 258002464);              // [1024][512]
    u16* w2T = (u16*)(base + 259051040);              // [1024][512]
    u16* w3T = (u16*)(base + 260099616);              // [256][512] -> end 260361760

    const int E = N_EDGES, M = N_NODES;
    const int nblk = (M + 255) / 256;

    // ---- CSR build ----
    zero4_kernel<<<(25154 + 255) / 256, 256, 0, stream>>>((float4*)d_ws, 25154);
    hist_kernel<<<(E + 255) / 256, 256, 0, stream>>>(dst, row_start, E);
    scan_reduce<<<nblk, 256, 0, stream>>>(row_start, bsums, M);
    scan_sums<<<1, 256, 0, stream>>>(bsums, nblk);
    scan_final<<<nblk, 256, 0, stream>>>(row_start, bsums, M);
    fill_kernel<<<(E + 255) / 256, 256, 0, stream>>>(src, dst, row_start, cursor,
                                                     csr_src, E);

    // ---- conversions: x -> bf16; weights -> WT [N][K] bf16, l/r concat ----
    convert_bf16<<<(3200000 + 255) / 256, 256, 0, stream>>>(x, xb, 3200000);
    transpose_w<<<dim3(16, 16), 256, 0, stream>>>(W1_l, w1T, 512, 512);
    transpose_w<<<dim3(16, 16), 256, 0, stream>>>(W1_r, w1T + 512 * 512, 512, 512);
    transpose_w<<<dim3(16, 16), 256, 0, stream>>>(W2_l, w2T, 512, 512);
    transpose_w<<<dim3(16, 16), 256, 0, stream>>>(W2_r, w2T + 512 * 512, 512, 512);
    transpose_w<<<dim3(4, 16), 256, 0, stream>>>(W3_l, w3T, 512, 128);
    transpose_w<<<dim3(4, 16), 256, 0, stream>>>(W3_r, w3T + 128 * 512, 512, 128);

    const int nStrips = (M + 63) / 64;                   // 782 (64-row strips)
    // L1/2: 16 col-tiles of 64 -> grid = ceil(782/8)*8*16 = 12544
    // L3:   4 col-tiles of 64  -> grid = ceil(782/8)*8*4  = 3136
    const int grid12 = ((nStrips + 7) / 8) * 8 * 16;
    const int grid3  = ((nStrips + 7) / 8) * 8 * 4;
    const int gblocks = (M * 64 + 255) / 256;            // wave/node
    const int g16blocks = (M + 15) / 16;                 // 16 lanes/node

    // ---- layer 1: Y = x@[W1_l|W1_r]; h1 = relu(gather(Yl)+Yr+b1) ----
    gemm_bf16<<<grid12, 64, 0, stream>>>(xb, w1T, Yl, Yr, M, 512, nStrips, 16);
    gather_add_relu512<<<gblocks, 256, 0, stream>>>(Yl, Yr, b1, row_start,
                                                    csr_src, h1b, M);
    // ---- layer 2 ----
    gemm_bf16<<<grid12, 64, 0, stream>>>(h1b, w2T, Yl, Yr, M, 512, nStrips, 16);
    gather_add_relu512<<<gblocks, 256, 0, stream>>>(Yl, Yr, b2, row_start,
                                                    csr_src, h2b, M);
    // ---- layer 3: Y3 = h2@[W3_l|W3_r]; out = lsm(gather(Y3l)+Y3r+b3) ----
    gemm_bf16<<<grid3, 64, 0, stream>>>(h2b, w3T, Yl, Yr, M, 128, nStrips, 4);
    gather_add_lsm128<<<g16blocks, 256, 0, stream>>>(Yl, Yr, b3, row_start,
                                                     csr_src, out, M);
}

// Round 7
// 656.922 us; speedup vs baseline: 1.1792x; 1.1792x over previous
//
#include <hip/hip_runtime.h>
#include <hip/hip_bf16.h>

// GraphSAGE 3-layer, N=50000 nodes, E=400000 edges, dims 512->512->512->128.
// Round 14 -> 15:
//  (a) GEMM: exact revert to R1's best (108us): 128x128, 4 waves, dbuf LDS,
//      global_load_lds (lane-linear dest, source-swizzled), 1 barrier/iter.
//      Six structural GEMM variants (R1-R6) proved it's at its shape-limited
//      band (476 TF at K=512; m102 curve). GEMM is NOT the main pot anymore.
//  (b) GATHERS (est. ~380us combined, never touched): neighbor loop issues
//      one 1KB row-read per neighbor then dependent VALU -> one exposed
//      L2/L3 round-trip (~500cy) per neighbor, ~8/node. UNROLL 4-DEEP:
//      broadcast 4 src idx, issue 4 independent uint4 loads back-to-back,
//      then accumulate. 4x fewer exposed latencies; corroborated by R4
//      (+40us when row-reads were split 4-way -> gathers are latency-bound).

#define N_NODES 50000
#define N_EDGES 400000

typedef unsigned short u16;
typedef unsigned int u32;
typedef __attribute__((ext_vector_type(8))) short short8;
typedef __attribute__((ext_vector_type(4))) float floatx4;

#define ASYNC16(g, l)                                                      \
    __builtin_amdgcn_global_load_lds(                                      \
        (const __attribute__((address_space(1))) void*)(g),                \
        (__attribute__((address_space(3))) void*)(l), 16, 0, 0)

__device__ __forceinline__ u16 f32_to_bf16(float f) {
    u32 u = __float_as_uint(f);
    u32 r = 0x7FFFu + ((u >> 16) & 1u);
    return (u16)((u + r) >> 16);
}
__device__ __forceinline__ float bf16_to_f32(u32 lo16) {
    return __uint_as_float(lo16 << 16);
}

__global__ __launch_bounds__(256) void zero4_kernel(float4* __restrict__ p, int n4) {
    int i = blockIdx.x * 256 + threadIdx.x;
    if (i < n4) p[i] = make_float4(0.f, 0.f, 0.f, 0.f);
}

__global__ __launch_bounds__(256) void hist_kernel(const int* __restrict__ dst,
                                                   int* __restrict__ deg, int E) {
    int e = blockIdx.x * 256 + threadIdx.x;
    if (e < E) atomicAdd(&deg[dst[e]], 1);
}

__global__ __launch_bounds__(256) void scan_reduce(const int* __restrict__ v,
                                                   int* __restrict__ bsums, int n) {
    __shared__ int sh[256];
    int i = blockIdx.x * 256 + threadIdx.x;
    sh[threadIdx.x] = (i < n) ? v[i] : 0;
    __syncthreads();
    for (int off = 128; off > 0; off >>= 1) {
        if (threadIdx.x < off) sh[threadIdx.x] += sh[threadIdx.x + off];
        __syncthreads();
    }
    if (threadIdx.x == 0) bsums[blockIdx.x] = sh[0];
}

__global__ __launch_bounds__(256) void scan_sums(int* __restrict__ bsums, int nb) {
    __shared__ int sh[256];
    int t = threadIdx.x;
    int val = (t < nb) ? bsums[t] : 0;
    sh[t] = val;
    __syncthreads();
    for (int off = 1; off < 256; off <<= 1) {
        int v = (t >= off) ? sh[t - off] : 0;
        __syncthreads();
        sh[t] += v;
        __syncthreads();
    }
    if (t < nb) bsums[t] = sh[t] - val;
}

__global__ __launch_bounds__(256) void scan_final(int* __restrict__ v,
                                                  const int* __restrict__ bsums, int n) {
    __shared__ int sh[256];
    int t = threadIdx.x;
    int i = blockIdx.x * 256 + t;
    int val = (i < n) ? v[i] : 0;
    sh[t] = val;
    __syncthreads();
    for (int off = 1; off < 256; off <<= 1) {
        int x = (t >= off) ? sh[t - off] : 0;
        __syncthreads();
        sh[t] += x;
        __syncthreads();
    }
    int excl = sh[t] - val + bsums[blockIdx.x];
    if (i < n) v[i] = excl;
    if (i == n - 1) v[n] = excl + val;
}

__global__ __launch_bounds__(256) void fill_kernel(const int* __restrict__ src,
                                                   const int* __restrict__ dst,
                                                   const int* __restrict__ row_start,
                                                   int* __restrict__ cursor,
                                                   int* __restrict__ csr_src, int E) {
    int e = blockIdx.x * 256 + threadIdx.x;
    if (e < E) {
        int d = dst[e];
        int pos = row_start[d] + atomicAdd(&cursor[d], 1);
        csr_src[pos] = src[e];
    }
}

// f32 [n8*8] -> bf16, 8 elems/thread
__global__ __launch_bounds__(256) void convert_bf16(const float* __restrict__ in,
                                                    u16* __restrict__ out, int n8) {
    int i = blockIdx.x * 256 + threadIdx.x;
    if (i >= n8) return;
    const float4* p = (const float4*)in + (size_t)i * 2;
    float4 v0 = p[0], v1 = p[1];
    uint4 o;
    o.x = (u32)f32_to_bf16(v0.x) | ((u32)f32_to_bf16(v0.y) << 16);
    o.y = (u32)f32_to_bf16(v0.z) | ((u32)f32_to_bf16(v0.w) << 16);
    o.z = (u32)f32_to_bf16(v1.x) | ((u32)f32_to_bf16(v1.y) << 16);
    o.w = (u32)f32_to_bf16(v1.z) | ((u32)f32_to_bf16(v1.w) << 16);
    ((uint4*)out)[i] = o;
}

// W [K][N] f32 -> WT [N][K] bf16, 32x32 tiles
__global__ __launch_bounds__(256) void transpose_w(const float* __restrict__ W,
                                                   u16* __restrict__ WT,
                                                   int K, int N) {
    __shared__ float t[32][33];
    int n0 = blockIdx.x * 32, k0 = blockIdx.y * 32;
    int c = threadIdx.x & 31, r0 = threadIdx.x >> 5;
    for (int r = r0; r < 32; r += 8)
        t[r][c] = W[(size_t)(k0 + r) * N + n0 + c];
    __syncthreads();
    for (int r = r0; r < 32; r += 8)
        WT[(size_t)(n0 + r) * K + k0 + c] = f32_to_bf16(t[c][r]);
}

// C = A @ BT' (BT stored [N][512], k-contig), single pass K=512, bf16 out.
// 128x128 tile, dbuf LDS, global_load_lds staging (lane-linear dest,
// source-swizzled), 1 barrier/iter, swapped-operand MFMA. (R1 variant.)
__global__ __launch_bounds__(256) void gemm_bf16(
    const u16* __restrict__ A, const u16* __restrict__ BT,
    u16* __restrict__ Cl, u16* __restrict__ Cr,
    int M, int split, int nStrips, int nCols) {
    __shared__ u16 As[2][4096];  // 128 rows x 32 u16 (64B), lane-linear
    __shared__ u16 Bs[2][4096];

    const int grp = 8 * nCols;
    int b = blockIdx.x;
    int strip = (b / grp) * 8 + (b & 7);   // col-tiles of a strip share b%8 -> XCD
    int colt = (b % grp) >> 3;
    if (strip >= nStrips) return;
    const int row0 = strip * 128, col0 = colt * 128;

    const int t = threadIdx.x;
    const int w = t >> 6, lane = t & 63;
    const int wm = (w >> 1) * 64, wn = (w & 1) * 64;
    const int l15 = lane & 15, kq = lane >> 4;
    const int swz = (l15 >> 1) & 3;        // fragment-read swizzle bits

    floatx4 acc[4][4];
#pragma unroll
    for (int i = 0; i < 4; ++i)
#pragma unroll
        for (int j = 0; j < 4; ++j) acc[i][j] = floatx4{0.f, 0.f, 0.f, 0.f};

    const int sr = t >> 2;
    const int sc = t & 3;
    const int swzS = (sr >> 1) & 3;        // same bits for sr and sr+64
    const size_t aA0 = (size_t)min(row0 + sr, M - 1) * 512 + (sc ^ swzS) * 8;
    const size_t aA1 = (size_t)min(row0 + 64 + sr, M - 1) * 512 + (sc ^ swzS) * 8;
    const size_t aB0 = (size_t)(col0 + sr) * 512 + (sc ^ swzS) * 8;
    const size_t aB1 = (size_t)(col0 + 64 + sr) * 512 + (sc ^ swzS) * 8;
    const int d0 = w * 512;        // u16 index: wave-uniform LDS dest, part 0
    const int d1 = 2048 + w * 512; // rows +64

    auto stage = [&](int it, int buf) {
        const int eff = it * 32;
        ASYNC16(A + aA0 + eff, &As[buf][d0]);
        ASYNC16(A + aA1 + eff, &As[buf][d1]);
        ASYNC16(BT + aB0 + eff, &Bs[buf][d0]);
        ASYNC16(BT + aB1 + eff, &Bs[buf][d1]);
    };

    stage(0, 0);
    __syncthreads();  // vmcnt(0) drain: buf0 ready
    for (int it = 0; it < 16; ++it) {
        const int buf = it & 1;
        if (it + 1 < 16) stage(it + 1, buf ^ 1);  // in flight across the MFMAs

        const int kc = (kq ^ swz) * 8;      // swizzled chunk for this lane
        short8 a[4], bfr[4];
#pragma unroll
        for (int mt = 0; mt < 4; ++mt)
            a[mt] = *(const short8*)&As[buf][(wm + mt * 16 + l15) * 32 + kc];
#pragma unroll
        for (int nt = 0; nt < 4; ++nt)
            bfr[nt] = *(const short8*)&Bs[buf][(wn + nt * 16 + l15) * 32 + kc];
        // Swapped operands: D = C^T; lane l15 = C-row, regs = 4 consecutive cols
#pragma unroll
        for (int mt = 0; mt < 4; ++mt)
#pragma unroll
            for (int nt = 0; nt < 4; ++nt)
                acc[mt][nt] = __builtin_amdgcn_mfma_f32_16x16x32_bf16(
                    bfr[nt], a[mt], acc[mt][nt], 0, 0, 0);
        __syncthreads();  // drains this iter's stage -> buf^1 ready
    }

    // Epilogue (C^T layout): row = wm+mt*16+l15, cols = wn+nt*16+kq*4..+3
    u16* __restrict__ Cbase = (col0 < split) ? Cl : Cr;
    const int cadj = (col0 < split) ? col0 : (col0 - split);
#pragma unroll
    for (int mt = 0; mt < 4; ++mt) {
        int row = row0 + wm + mt * 16 + l15;
        if (row >= M) continue;
#pragma unroll
        for (int nt = 0; nt < 4; ++nt) {
            int c0 = cadj + wn + nt * 16 + kq * 4;
            uint2 o;
            o.x = (u32)f32_to_bf16(acc[mt][nt][0]) |
                  ((u32)f32_to_bf16(acc[mt][nt][1]) << 16);
            o.y = (u32)f32_to_bf16(acc[mt][nt][2]) |
                  ((u32)f32_to_bf16(acc[mt][nt][3]) << 16);
            *(uint2*)(Cbase + (size_t)row * split + c0) = o;
        }
    }
}

__device__ __forceinline__ void acc8(float* a, uint4 v) {
    a[0] += bf16_to_f32(v.x & 0xffffu); a[1] += bf16_to_f32(v.x >> 16);
    a[2] += bf16_to_f32(v.y & 0xffffu); a[3] += bf16_to_f32(v.y >> 16);
    a[4] += bf16_to_f32(v.z & 0xffffu); a[5] += bf16_to_f32(v.z >> 16);
    a[6] += bf16_to_f32(v.w & 0xffffu); a[7] += bf16_to_f32(v.w >> 16);
}

// h[node] = relu(mean(Yl[src]) + Yr[node] + bias), D=512 bf16.
// One wave per node; lane covers 8 cols (uint4). Neighbor loop unrolled
// 4-deep: 4 independent row-loads in flight per step (latency hiding).
__global__ __launch_bounds__(256) void gather_add_relu512(
    const u16* __restrict__ Yl, const u16* __restrict__ Yr,
    const float* __restrict__ bias,
    const int* __restrict__ row_start, const int* __restrict__ csr_src,
    u16* __restrict__ h, int M) {
    int node = (blockIdx.x * 256 + threadIdx.x) >> 6;
    int lane = threadIdx.x & 63;
    if (node >= M) return;
    int beg = row_start[node], end = row_start[node + 1];
    float a[8] = {0.f, 0.f, 0.f, 0.f, 0.f, 0.f, 0.f, 0.f};
    for (int c = beg; c < end; c += 64) {
        int nb = min(64, end - c);
        int eid = (lane < nb) ? csr_src[c + lane] : 0;
        int i = 0;
        for (; i + 4 <= nb; i += 4) {
            int s0 = __shfl(eid, i);
            int s1 = __shfl(eid, i + 1);
            int s2 = __shfl(eid, i + 2);
            int s3 = __shfl(eid, i + 3);
            uint4 v0 = ((const uint4*)(Yl + (size_t)s0 * 512))[lane];
            uint4 v1 = ((const uint4*)(Yl + (size_t)s1 * 512))[lane];
            uint4 v2 = ((const uint4*)(Yl + (size_t)s2 * 512))[lane];
            uint4 v3 = ((const uint4*)(Yl + (size_t)s3 * 512))[lane];
            acc8(a, v0); acc8(a, v1); acc8(a, v2); acc8(a, v3);
        }
        for (; i < nb; ++i) {
            int s = __shfl(eid, i);
            uint4 v = ((const uint4*)(Yl + (size_t)s * 512))[lane];
            acc8(a, v);
        }
    }
    float inv = 1.0f / fmaxf((float)(end - beg), 1.0f);
    uint4 yr = ((const uint4*)(Yr + (size_t)node * 512))[lane];
    float4 b0 = ((const float4*)bias)[lane * 2];
    float4 b1 = ((const float4*)bias)[lane * 2 + 1];
    float v0 = fmaxf(a[0] * inv + bf16_to_f32(yr.x & 0xffffu) + b0.x, 0.f);
    float v1 = fmaxf(a[1] * inv + bf16_to_f32(yr.x >> 16)     + b0.y, 0.f);
    float v2 = fmaxf(a[2] * inv + bf16_to_f32(yr.y & 0xffffu) + b0.z, 0.f);
    float v3 = fmaxf(a[3] * inv + bf16_to_f32(yr.y >> 16)     + b0.w, 0.f);
    float v4 = fmaxf(a[4] * inv + bf16_to_f32(yr.z & 0xffffu) + b1.x, 0.f);
    float v5 = fmaxf(a[5] * inv + bf16_to_f32(yr.z >> 16)     + b1.y, 0.f);
    float v6 = fmaxf(a[6] * inv + bf16_to_f32(yr.w & 0xffffu) + b1.z, 0.f);
    float v7 = fmaxf(a[7] * inv + bf16_to_f32(yr.w >> 16)     + b1.w, 0.f);
    uint4 o;
    o.x = (u32)f32_to_bf16(v0) | ((u32)f32_to_bf16(v1) << 16);
    o.y = (u32)f32_to_bf16(v2) | ((u32)f32_to_bf16(v3) << 16);
    o.z = (u32)f32_to_bf16(v4) | ((u32)f32_to_bf16(v5) << 16);
    o.w = (u32)f32_to_bf16(v6) | ((u32)f32_to_bf16(v7) << 16);
    ((uint4*)(h + (size_t)node * 512))[lane] = o;
}

// out[node] = log_softmax(mean(Yl[src]) + Yr[node] + bias), D=128, f32 out.
// 16 lanes per node (4 nodes/wave); lane covers 8 cols. Neighbor loop
// unrolled 4-deep.
__global__ __launch_bounds__(256) void gather_add_lsm128(
    const u16* __restrict__ Yl, const u16* __restrict__ Yr,
    const float* __restrict__ bias,
    const int* __restrict__ row_start, const int* __restrict__ csr_src,
    float* __restrict__ out, int M) {
    int node = blockIdx.x * 16 + (threadIdx.x >> 4);
    int lane = threadIdx.x & 63;
    int li = lane & 15;
    int gbase = lane & 48;      // group base lane within wave
    if (node >= M) return;
    int beg = row_start[node], end = row_start[node + 1];
    float a[8] = {0.f, 0.f, 0.f, 0.f, 0.f, 0.f, 0.f, 0.f};
    for (int c = beg; c < end; c += 16) {
        int nb = min(16, end - c);
        int eid = (li < nb) ? csr_src[c + li] : 0;
        int i = 0;
        for (; i + 4 <= nb; i += 4) {
            int s0 = __shfl(eid, gbase + i);
            int s1 = __shfl(eid, gbase + i + 1);
            int s2 = __shfl(eid, gbase + i + 2);
            int s3 = __shfl(eid, gbase + i + 3);
            uint4 v0 = ((const uint4*)(Yl + (size_t)s0 * 128))[li];
            uint4 v1 = ((const uint4*)(Yl + (size_t)s1 * 128))[li];
            uint4 v2 = ((const uint4*)(Yl + (size_t)s2 * 128))[li];
            uint4 v3 = ((const uint4*)(Yl + (size_t)s3 * 128))[li];
            acc8(a, v0); acc8(a, v1); acc8(a, v2); acc8(a, v3);
        }
        for (; i < nb; ++i) {
            int s = __shfl(eid, gbase + i);
            uint4 v = ((const uint4*)(Yl + (size_t)s * 128))[li];
            acc8(a, v);
        }
    }
    float inv = 1.0f / fmaxf((float)(end - beg), 1.0f);
    uint4 yr = ((const uint4*)(Yr + (size_t)node * 128))[li];
    float4 b0 = ((const float4*)bias)[li * 2];
    float4 b1 = ((const float4*)bias)[li * 2 + 1];
    float v[8];
    v[0] = a[0] * inv + bf16_to_f32(yr.x & 0xffffu) + b0.x;
    v[1] = a[1] * inv + bf16_to_f32(yr.x >> 16)     + b0.y;
    v[2] = a[2] * inv + bf16_to_f32(yr.y & 0xffffu) + b0.z;
    v[3] = a[3] * inv + bf16_to_f32(yr.y >> 16)     + b0.w;
    v[4] = a[4] * inv + bf16_to_f32(yr.z & 0xffffu) + b1.x;
    v[5] = a[5] * inv + bf16_to_f32(yr.z >> 16)     + b1.y;
    v[6] = a[6] * inv + bf16_to_f32(yr.w & 0xffffu) + b1.z;
    v[7] = a[7] * inv + bf16_to_f32(yr.w >> 16)     + b1.w;
    float m = v[0];
#pragma unroll
    for (int j = 1; j < 8; ++j) m = fmaxf(m, v[j]);
#pragma unroll
    for (int off = 1; off < 16; off <<= 1) m = fmaxf(m, __shfl_xor(m, off));
    float s = 0.f;
#pragma unroll
    for (int j = 0; j < 8; ++j) s += expf(v[j] - m);
#pragma unroll
    for (int off = 1; off < 16; off <<= 1) s += __shfl_xor(s, off);
    float ls = m + logf(s);
    float* p = out + (size_t)node * 128 + li * 8;
    *(float4*)p       = make_float4(v[0] - ls, v[1] - ls, v[2] - ls, v[3] - ls);
    *(float4*)(p + 4) = make_float4(v[4] - ls, v[5] - ls, v[6] - ls, v[7] - ls);
}

extern "C" void kernel_launch(void* const* d_in, const int* in_sizes, int n_in,
                              void* d_out, int out_size, void* d_ws, size_t ws_size,
                              hipStream_t stream) {
    const float* x    = (const float*)d_in[0];
    const int*   ei   = (const int*)d_in[1];
    const float* W1_l = (const float*)d_in[2];
    const float* b1   = (const float*)d_in[3];
    const float* W1_r = (const float*)d_in[4];
    const float* W2_l = (const float*)d_in[5];
    const float* b2   = (const float*)d_in[6];
    const float* W2_r = (const float*)d_in[7];
    const float* W3_l = (const float*)d_in[8];
    const float* b3   = (const float*)d_in[9];
    const float* W3_r = (const float*)d_in[10];
    float* out = (float*)d_out;

    const int* src = ei;
    const int* dst = ei + N_EDGES;

    // Workspace layout (bytes from base):
    char* base = (char*)d_ws;
    int* row_start = (int*)(base);                    // 50052 ints
    int* cursor    = (int*)(base + 200208);           // 50052 ints
    int* bsums     = (int*)(base + 400416);           // 512 ints
    int* csr_src   = (int*)(base + 402464);           // 400000 ints -> end 2002464
    u16* xb  = (u16*)(base + 2002464);                // [M][512] bf16
    u16* h1b = (u16*)(base + 53202464);               // [M][512]
    u16* h2b = (u16*)(base + 104402464);              // [M][512]
    u16* Yl  = (u16*)(base + 155602464);              // [M][512] (layer3: [M][128])
    u16* Yr  = (u16*)(base + 206802464);              // [M][512] (layer3: [M][128])
    u16* w1T = (u16*)(base + 258002464);              // [1024][512]
    u16* w2T = (u16*)(base + 259051040);              // [1024][512]
    u16* w3T = (u16*)(base + 260099616);              // [256][512] -> end 260361760

    const int E = N_EDGES, M = N_NODES;
    const int nblk = (M + 255) / 256;

    // ---- CSR build ----
    zero4_kernel<<<(25154 + 255) / 256, 256, 0, stream>>>((float4*)d_ws, 25154);
    hist_kernel<<<(E + 255) / 256, 256, 0, stream>>>(dst, row_start, E);
    scan_reduce<<<nblk, 256, 0, stream>>>(row_start, bsums, M);
    scan_sums<<<1, 256, 0, stream>>>(bsums, nblk);
    scan_final<<<nblk, 256, 0, stream>>>(row_start, bsums, M);
    fill_kernel<<<(E + 255) / 256, 256, 0, stream>>>(src, dst, row_start, cursor,
                                                     csr_src, E);

    // ---- conversions: x -> bf16; weights -> WT [N][K] bf16, l/r concat ----
    convert_bf16<<<(3200000 + 255) / 256, 256, 0, stream>>>(x, xb, 3200000);
    transpose_w<<<dim3(16, 16), 256, 0, stream>>>(W1_l, w1T, 512, 512);
    transpose_w<<<dim3(16, 16), 256, 0, stream>>>(W1_r, w1T + 512 * 512, 512, 512);
    transpose_w<<<dim3(16, 16), 256, 0, stream>>>(W2_l, w2T, 512, 512);
    transpose_w<<<dim3(16, 16), 256, 0, stream>>>(W2_r, w2T + 512 * 512, 512, 512);
    transpose_w<<<dim3(4, 16), 256, 0, stream>>>(W3_l, w3T, 512, 128);
    transpose_w<<<dim3(4, 16), 256, 0, stream>>>(W3_r, w3T + 128 * 512, 512, 128);

    const int nStrips = (M + 127) / 128;                 // 391
    const int grid8 = ((nStrips + 7) / 8) * 64;          // 3136 (nCols=8)
    const int grid2 = ((nStrips + 7) / 8) * 16;          // 784  (nCols=2)
    const int gblocks = (M * 64 + 255) / 256;            // wave/node
    const int g16blocks = (M + 15) / 16;                 // 16 lanes/node

    // ---- layer 1: Y = x@[W1_l|W1_r]; h1 = relu(gather(Yl)+Yr+b1) ----
    gemm_bf16<<<grid8, 256, 0, stream>>>(xb, w1T, Yl, Yr, M, 512, nStrips, 8);
    gather_add_relu512<<<gblocks, 256, 0, stream>>>(Yl, Yr, b1, row_start,
                                                    csr_src, h1b, M);
    // ---- layer 2 ----
    gemm_bf16<<<grid8, 256, 0, stream>>>(h1b, w2T, Yl, Yr, M, 512, nStrips, 8);
    gather_add_relu512<<<gblocks, 256, 0, stream>>>(Yl, Yr, b2, row_start,
                                                    csr_src, h2b, M);
    // ---- layer 3: Y3 = h2@[W3_l|W3_r]; out = lsm(gather(Y3l)+Y3r+b3) ----
    gemm_bf16<<<grid2, 256, 0, stream>>>(h2b, w3T, Yl, Yr, M, 128, nStrips, 2);
    gather_add_lsm128<<<g16blocks, 256, 0, stream>>>(Yl, Yr, b3, row_start,
                                                     csr_src, out, M);
}